// Round 9
// baseline (6162.839 us; speedup 1.0000x reference)
//
#include <hip/hip_runtime.h>
#include <cmath>

#define BB 64
#define TT 512
#define II 256
#define HH 1024
#define OO 512

typedef short bf8 __attribute__((ext_vector_type(8)));    // 8 bf16 vals
typedef float f32x4 __attribute__((ext_vector_type(4)));
typedef unsigned long long u64;

#define MFMA(a, b, c) __builtin_amdgcn_mfma_f32_16x16x32_bf16((a), (b), (c), 0, 0, 0)

__device__ __forceinline__ unsigned short f2bf(float f) {
    unsigned u = __float_as_uint(f);
    return (unsigned short)((u + 0x7fffu + ((u >> 16) & 1u)) >> 16);
}
__device__ __forceinline__ float bf2f(unsigned short h) {
    return __uint_as_float((unsigned)h << 16);
}
__device__ __forceinline__ void split8(const float* v, bf8& hi, bf8& lo) {
#pragma unroll
    for (int j = 0; j < 8; ++j) {
        unsigned short h = f2bf(v[j]);
        float r = v[j] - bf2f(h);
        hi[j] = (short)h;
        lo[j] = (short)f2bf(r);
    }
}
__device__ __forceinline__ void ld8(float* v, const float* p) {
    *(float4*)v       = *(const float4*)p;
    *(float4*)(v + 4) = *(const float4*)(p + 4);
}

// L3-coherent 16B load / store (sc1 path) — proven R6/R8.
__device__ __forceinline__ bf8 load_h(const void* p) {
    u64 a = __hip_atomic_load((const u64*)p, __ATOMIC_RELAXED, __HIP_MEMORY_SCOPE_AGENT);
    u64 b = __hip_atomic_load((const u64*)((const char*)p + 8),
                              __ATOMIC_RELAXED, __HIP_MEMORY_SCOPE_AGENT);
    union { u64 q[2]; bf8 v; } u;
    u.q[0] = a; u.q[1] = b;
    return u.v;
}
__device__ __forceinline__ void store16(void* p, u64 a, u64 b) {
    __hip_atomic_store((u64*)p, a, __ATOMIC_RELAXED, __HIP_MEMORY_SCOPE_AGENT);
    __hip_atomic_store((u64*)((char*)p + 8), b, __ATOMIC_RELAXED, __HIP_MEMORY_SCOPE_AGENT);
}
__device__ __forceinline__ unsigned ld_flag(const void* p) {
    return __hip_atomic_load((const unsigned*)p, __ATOMIC_RELAXED, __HIP_MEMORY_SCOPE_AGENT);
}
__device__ __forceinline__ void st_flag(void* p, unsigned v) {
    __hip_atomic_store((unsigned*)p, v, __ATOMIC_RELAXED, __HIP_MEMORY_SCOPE_AGENT);
}

// h layout per (layer, slot, group) 64KB buffer: 32 chunks x 64 lanes x 32B.
// Element h[b][k]: chunk k>>5, lane (b&15)+16*((k&31)>>3), j=k&7: hi j*2, lo j*2+16.
//
// Grid 256 x 512. Logical: grp=bid&3 (16 batches), layer=(bid>>2)&1, slot=bid>>3
// -> rows slot*32..+31 of its layer. 8 waves x K-slice 128 (4 chunks).
// L0-WG interval t (0..TT-1): h1(t) = tanh(x(t)@Wih0^T + b + h1(t-1)@Whh0^T)
// L1-WG interval s (1..TT):   h2(s-1) = tanh(h1(s-1)@Wih1^T + b + h2(s-2)@Whh1^T)
// flagA[grp][slot] = t+1 after h1(t); flagB[grp][slot] = s+1 after h2(s-1).
// L0@t waits flagA>=t & flagB>=t-2 (h1 depth 4); L1@s waits flagA>=s & (s>=2) flagB>=s (h2 depth 2).
__global__ __launch_bounds__(512, 2) void rnn_split(
    const float* __restrict__ x,
    const float* __restrict__ Wih0, const float* __restrict__ Whh0,
    const float* __restrict__ bih0, const float* __restrict__ bhh0,
    const float* __restrict__ Wih1, const float* __restrict__ Whh1,
    const float* __restrict__ bih1, const float* __restrict__ bhh1,
    const float* __restrict__ Wfc,  const float* __restrict__ bfc,
    float* __restrict__ out, float* __restrict__ ws)
{
    __shared__ float shmem[4864];          // ps [8][2][16][17]=4352 | staging 512 fl (2KB)
    float* ps = shmem;
    char*  staging = (char*)(shmem + 4352);

    const int tid  = threadIdx.x;
    const int w    = tid >> 6;
    const int lane = tid & 63;
    const int col  = lane & 15;
    const int kg   = lane >> 4;
    const int bid  = blockIdx.x;
    const int grp   = bid & 3;
    const int layer = (bid >> 2) & 1;
    const int slot  = bid >> 3;            // 0..31
    const int rb    = slot * 32;
    const int b0    = grp * 16;

    char* wsB    = (char*)ws;
    char* flagA  = wsB;                    // [grp*32+slot]*16, 2KB
    char* flagB  = wsB + 2048;             // same, 2KB
    char* h1base = wsB + 8192;             // [slot4][grp4] 64KB = 1MB
    char* h2base = h1base + 4 * 4 * 65536; // [slot2][grp4] 64KB = 512KB

    // ---- weight preload into VGPRs (once) ----
    bf8 wxh[2], wxl[2];                    // L0: Wih0 (1 chunk, 2 tiles)
    bf8 wah[2][4], wal[2][4];              // L0: Whh0 | L1: Wih1
    bf8 wbh[2][4], wbl[2][4];              // L1: Whh1
    {
        float v[8];
        if (layer == 0) {
            #pragma unroll
            for (int n = 0; n < 2; ++n) {
                ld8(v, Wih0 + (size_t)(rb + n * 16 + col) * II + (w * 32 + kg * 8));
                split8(v, wxh[n], wxl[n]);
                #pragma unroll
                for (int c = 0; c < 4; ++c) {
                    ld8(v, Whh0 + (size_t)(rb + n * 16 + col) * HH + (w * 128 + c * 32 + kg * 8));
                    split8(v, wah[n][c], wal[n][c]);
                }
            }
        } else {
            #pragma unroll
            for (int n = 0; n < 2; ++n)
                #pragma unroll
                for (int c = 0; c < 4; ++c) {
                    ld8(v, Wih1 + (size_t)(rb + n * 16 + col) * HH + (w * 128 + c * 32 + kg * 8));
                    split8(v, wah[n][c], wal[n][c]);
                    ld8(v, Whh1 + (size_t)(rb + n * 16 + col) * HH + (w * 128 + c * 32 + kg * 8));
                    split8(v, wbh[n][c], wbl[n][c]);
                }
        }
    }

    // ---- epilogue role constants: thread -> (channel ekk, batch b) ----
    const int ekk = tid >> 4;              // 0..31 (row within WG)
    const int eb  = tid & 15;              // batch
    const int R   = rb + ekk;
    const float bsum = layer ? (bih1[R] + bhh1[R]) : (bih0[R] + bhh0[R]);
    const int stg_off = (eb + 16 * (ekk >> 3)) * 32 + (ekk & 7) * 2;
    char* myflag = (layer ? flagB : flagA) + (size_t)(grp * 32 + slot) * 16;

    const int tBeg = layer ? 1 : 0;
    const int tEnd = layer ? TT : TT - 1;

    for (int t = tBeg; t <= tEnd; ++t) {
        // ---- wait on producer flags (wave 0 polls, lanes split A/B) ----
        {
            const unsigned tA = (unsigned)t;
            const unsigned tB = layer ? ((t >= 2) ? (unsigned)t : 0u)
                                      : ((t >= 3) ? (unsigned)(t - 2) : 0u);
            if (w == 0) {
                const char* pa = flagA + (size_t)grp * 512 + (size_t)(lane & 31) * 16;
                const char* pb = flagB + (size_t)grp * 512 + (size_t)(lane & 31) * 16;
                for (;;) {
                    unsigned f = (lane < 32) ? ld_flag(pa) : ld_flag(pb);
                    bool ok = (lane < 32) ? (f >= tA) : (f >= tB);
                    if (__all(ok)) break;
                    __builtin_amdgcn_s_sleep(1);
                }
            }
            __syncthreads();
        }

        f32x4 acc0 = {0.f, 0.f, 0.f, 0.f};
        f32x4 acc1 = {0.f, 0.f, 0.f, 0.f};

        if (layer == 0) {
            // x A-frag (1 chunk) + h1(t-1) A-frags (4 chunks)
            float v[8]; bf8 xh, xl;
            ld8(v, x + ((size_t)(b0 + col) * TT + t) * II + (w * 32 + kg * 8));
            split8(v, xh, xl);
            bf8 hh[4], hl[4];
            if (t >= 1) {
                const char* h1r = h1base + (size_t)(((t - 1) & 3) * 4 + grp) * 65536;
                #pragma unroll
                for (int c = 0; c < 4; ++c) {
                    const char* p = h1r + (size_t)(w * 4 + c) * 2048 + lane * 32;
                    hh[c] = load_h(p); hl[c] = load_h(p + 16);
                }
            }
            acc0 = MFMA(xh, wxh[0], acc0); acc0 = MFMA(xh, wxl[0], acc0); acc0 = MFMA(xl, wxh[0], acc0);
            acc1 = MFMA(xh, wxh[1], acc1); acc1 = MFMA(xh, wxl[1], acc1); acc1 = MFMA(xl, wxh[1], acc1);
            if (t >= 1) {
                #pragma unroll
                for (int c = 0; c < 4; ++c) {
                    acc0 = MFMA(hh[c], wah[0][c], acc0); acc0 = MFMA(hh[c], wal[0][c], acc0);
                    acc0 = MFMA(hl[c], wah[0][c], acc0);
                    acc1 = MFMA(hh[c], wah[1][c], acc1); acc1 = MFMA(hh[c], wal[1][c], acc1);
                    acc1 = MFMA(hl[c], wah[1][c], acc1);
                }
            }
        } else {
            // h1(s-1) + h2(s-2) A-frags (4 chunks each)
            bf8 hh[4], hl[4], gh[4], gl[4];
            const char* h1r = h1base + (size_t)(((t - 1) & 3) * 4 + grp) * 65536;
            #pragma unroll
            for (int c = 0; c < 4; ++c) {
                const char* p = h1r + (size_t)(w * 4 + c) * 2048 + lane * 32;
                hh[c] = load_h(p); hl[c] = load_h(p + 16);
            }
            if (t >= 2) {
                const char* h2r = h2base + (size_t)(((t - 2) & 1) * 4 + grp) * 65536;
                #pragma unroll
                for (int c = 0; c < 4; ++c) {
                    const char* p = h2r + (size_t)(w * 4 + c) * 2048 + lane * 32;
                    gh[c] = load_h(p); gl[c] = load_h(p + 16);
                }
            }
            #pragma unroll
            for (int c = 0; c < 4; ++c) {
                acc0 = MFMA(hh[c], wah[0][c], acc0); acc0 = MFMA(hh[c], wal[0][c], acc0);
                acc0 = MFMA(hl[c], wah[0][c], acc0);
                acc1 = MFMA(hh[c], wah[1][c], acc1); acc1 = MFMA(hh[c], wal[1][c], acc1);
                acc1 = MFMA(hl[c], wah[1][c], acc1);
            }
            if (t >= 2) {
                #pragma unroll
                for (int c = 0; c < 4; ++c) {
                    acc0 = MFMA(gh[c], wbh[0][c], acc0); acc0 = MFMA(gh[c], wbl[0][c], acc0);
                    acc0 = MFMA(gl[c], wbh[0][c], acc0);
                    acc1 = MFMA(gh[c], wbh[1][c], acc1); acc1 = MFMA(gh[c], wbl[1][c], acc1);
                    acc1 = MFMA(gl[c], wbh[1][c], acc1);
                }
            }
        }

        // ---- partials to LDS ----
        {
            float* pw = ps + w * 544;
            #pragma unroll
            for (int r = 0; r < 4; ++r) {
                pw[(kg * 4 + r) * 17 + col]       = acc0[r];
                pw[272 + (kg * 4 + r) * 17 + col] = acc1[r];
            }
        }
        __syncthreads();

        // ---- reduce + bias + tanh + hi/lo split -> LDS staging (2KB) ----
        {
            float s = bsum;
            #pragma unroll
            for (int wv = 0; wv < 8; ++wv)
                s += ps[wv * 544 + (ekk >> 4) * 272 + eb * 17 + (ekk & 15)];
            const float val = tanhf(s);
            const unsigned short hi = f2bf(val);
            const unsigned short lo = f2bf(val - bf2f(hi));
            *(unsigned short*)(staging + stg_off)      = hi;
            *(unsigned short*)(staging + stg_off + 16) = lo;
        }
        __syncthreads();

        // ---- coalesced 2KB chunk store (128 threads x 16B, sc1) ----
        if (tid < 128) {
            char* hw = layer
                ? (h2base + (size_t)(((t - 1) & 1) * 4 + grp) * 65536)
                : (h1base + (size_t)((t & 3) * 4 + grp) * 65536);
            const int off = (tid >> 1) * 32 + (tid & 1) * 16;
            const char* src = staging + off;
            store16(hw + (size_t)slot * 2048 + off,
                    *(const u64*)src, *(const u64*)(src + 8));
        }
        asm volatile("s_waitcnt vmcnt(0)" ::: "memory");
        __syncthreads();

        if (tid == 0) st_flag(myflag, (unsigned)(t + 1));
    }

    // ---- FC: wait all 128 flagB >= TT+1, then out[:, 2*bid..2*bid+1] ----
    if (tid < 128) {
        while (ld_flag(flagB + (size_t)tid * 16) < (unsigned)(TT + 1))
            __builtin_amdgcn_s_sleep(2);
    }
    __syncthreads();

    float* Wlds = shmem + 2304;
    ((float4*)Wlds)[tid] = ((const float4*)(Wfc + (size_t)(2 * bid) * HH))[tid];
    __syncthreads();

    float p0 = 0.f, p1 = 0.f;
    {
        const int gr = lane >> 4, bsub = lane & 15;
        const char* hb = h2base + (size_t)(((TT - 1) & 1) * 4 + gr) * 65536;
        #pragma unroll 4
        for (int k8 = w * 16; k8 < w * 16 + 16; ++k8) {
            const char* p = hb + (size_t)(k8 >> 2) * 2048
                          + (size_t)(bsub + ((k8 & 3) << 4)) * 32;
            bf8 hi = load_h(p), lo = load_h(p + 16);
            const int kb = k8 * 8;
            #pragma unroll
            for (int j = 0; j < 8; ++j) {
                float f = bf2f((unsigned short)hi[j]) + bf2f((unsigned short)lo[j]);
                p0 += f * Wlds[kb + j];
                p1 += f * Wlds[1024 + kb + j];
            }
        }
    }
    __syncthreads();
    shmem[(w * 64 + lane) * 2 + 0] = p0;
    shmem[(w * 64 + lane) * 2 + 1] = p1;
    __syncthreads();
    if (w < 2) {
        float s = bfc[2 * bid + w];
        #pragma unroll
        for (int j = 0; j < 8; ++j) s += shmem[(j * 64 + lane) * 2 + w];
        out[(size_t)lane * OO + 2 * bid + w] = s;
    }
}

extern "C" void kernel_launch(void* const* d_in, const int* in_sizes, int n_in,
                              void* d_out, int out_size, void* d_ws, size_t ws_size,
                              hipStream_t stream) {
    const float* x    = (const float*)d_in[0];
    const float* Wih0 = (const float*)d_in[1];
    const float* Whh0 = (const float*)d_in[2];
    const float* bih0 = (const float*)d_in[3];
    const float* bhh0 = (const float*)d_in[4];
    const float* Wih1 = (const float*)d_in[5];
    const float* Whh1 = (const float*)d_in[6];
    const float* bih1 = (const float*)d_in[7];
    const float* bhh1 = (const float*)d_in[8];
    const float* Wfc  = (const float*)d_in[9];
    const float* bfc  = (const float*)d_in[10];
    float* out = (float*)d_out;
    float* ws  = (float*)d_ws;

    // zero flag region every call (replay-safe); ws use: 8KB + 1.5MB
    hipMemsetAsync(d_ws, 0, 8192, stream);

    void* args[] = { (void*)&x,
                     (void*)&Wih0, (void*)&Whh0, (void*)&bih0, (void*)&bhh0,
                     (void*)&Wih1, (void*)&Whh1, (void*)&bih1, (void*)&bhh1,
                     (void*)&Wfc,  (void*)&bfc,  (void*)&out,  (void*)&ws };
    hipLaunchCooperativeKernel((void*)rnn_split, dim3(256), dim3(512),
                               args, 0, stream);
}

// Round 10
// 5715.394 us; speedup vs baseline: 1.0783x; 1.0783x over previous
//
#include <hip/hip_runtime.h>
#include <cmath>

#define BB 64
#define TT 512
#define II 256
#define HH 1024
#define OO 512
#define CHK 2112                         // 2048B chunk data + 64B footer line
#define H1SLOT (32 * CHK)                // one (slot,group) h1 buffer: 32 chunks
#define H2SLOT (32 * CHK)

typedef short bf8 __attribute__((ext_vector_type(8)));    // 8 bf16 vals
typedef float f32x4 __attribute__((ext_vector_type(4)));
typedef unsigned long long u64;

#define MFMA(a, b, c) __builtin_amdgcn_mfma_f32_16x16x32_bf16((a), (b), (c), 0, 0, 0)

__device__ __forceinline__ unsigned short f2bf(float f) {
    unsigned u = __float_as_uint(f);
    return (unsigned short)((u + 0x7fffu + ((u >> 16) & 1u)) >> 16);
}
__device__ __forceinline__ float bf2f(unsigned short h) {
    return __uint_as_float((unsigned)h << 16);
}
__device__ __forceinline__ void split8(const float* v, bf8& hi, bf8& lo) {
#pragma unroll
    for (int j = 0; j < 8; ++j) {
        unsigned short h = f2bf(v[j]);
        float r = v[j] - bf2f(h);
        hi[j] = (short)h;
        lo[j] = (short)f2bf(r);
    }
}
__device__ __forceinline__ void ld8(float* v, const float* p) {
    *(float4*)v       = *(const float4*)p;
    *(float4*)(v + 4) = *(const float4*)(p + 4);
}

// L3-coherent ops (sc1 path) — proven R6/R8/R9.
__device__ __forceinline__ bf8 load_h(const void* p) {
    u64 a = __hip_atomic_load((const u64*)p, __ATOMIC_RELAXED, __HIP_MEMORY_SCOPE_AGENT);
    u64 b = __hip_atomic_load((const u64*)((const char*)p + 8),
                              __ATOMIC_RELAXED, __HIP_MEMORY_SCOPE_AGENT);
    union { u64 q[2]; bf8 v; } u;
    u.q[0] = a; u.q[1] = b;
    return u.v;
}
__device__ __forceinline__ void store16(void* p, u64 a, u64 b) {
    __hip_atomic_store((u64*)p, a, __ATOMIC_RELAXED, __HIP_MEMORY_SCOPE_AGENT);
    __hip_atomic_store((u64*)((char*)p + 8), b, __ATOMIC_RELAXED, __HIP_MEMORY_SCOPE_AGENT);
}
__device__ __forceinline__ unsigned ld_flag(const void* p) {
    return __hip_atomic_load((const unsigned*)p, __ATOMIC_RELAXED, __HIP_MEMORY_SCOPE_AGENT);
}
__device__ __forceinline__ void st_flag(void* p, unsigned v) {
    __hip_atomic_store((unsigned*)p, v, __ATOMIC_RELAXED, __HIP_MEMORY_SCOPE_AGENT);
}

// h layout: per (layer, slot, group) buffer of 32 chunks. Chunk c (k=c*32..c*32+31):
// 64 lanes x 32B data at c*CHK + lane*32, footer u32 at c*CHK + 2048.
// Element h[b][k]: lane (b&15)+16*((k&31)>>3), j=k&7: hi j*2, lo j*2+16.
// Chunk c of a (layer,group) is produced entirely by that layer-group's WG slot c.
// Footer value = t+1 after the producer's step t (L0@t -> h1(t); L1@t -> h2(t-1)).
//
// Grid 256 x 512: grp=bid&3 (16 batches), layer=(bid>>2)&1, slot=bid>>3 (32 rows).
// Consumer waves poll per-chunk footers (lanes 0-3: h1, lanes 4-7: h2) then load —
// no WG-wide flag barrier, waves run decoupled. Dependency DAG (layer,t): acyclic.
__global__ __launch_bounds__(512, 2) void rnn_chunk(
    const float* __restrict__ x,
    const float* __restrict__ Wih0, const float* __restrict__ Whh0,
    const float* __restrict__ bih0, const float* __restrict__ bhh0,
    const float* __restrict__ Wih1, const float* __restrict__ Whh1,
    const float* __restrict__ bih1, const float* __restrict__ bhh1,
    const float* __restrict__ Wfc,  const float* __restrict__ bfc,
    float* __restrict__ out, float* __restrict__ ws)
{
    __shared__ float shmem[4864];          // ps [8][2][16][17]=4352 | staging 512 fl
    float* ps = shmem;
    char*  staging = (char*)(shmem + 4352);

    const int tid  = threadIdx.x;
    const int w    = tid >> 6;
    const int lane = tid & 63;
    const int col  = lane & 15;
    const int kg   = lane >> 4;
    const int bid  = blockIdx.x;
    const int grp   = bid & 3;
    const int layer = (bid >> 2) & 1;
    const int slot  = bid >> 3;            // 0..31
    const int rb    = slot * 32;
    const int b0    = grp * 16;

    char* wsB    = (char*)ws;
    char* h1base = wsB;                    // [4 slots][4 grp] * H1SLOT
    char* h2base = wsB + 16 * H1SLOT;      // [2 slots][4 grp] * H2SLOT

    // ---- weight preload into VGPRs (once) — identical to R9 ----
    bf8 wxh[2], wxl[2];                    // L0: Wih0
    bf8 wah[2][4], wal[2][4];              // L0: Whh0 | L1: Wih1
    bf8 wbh[2][4], wbl[2][4];              // L1: Whh1
    {
        float v[8];
        if (layer == 0) {
            #pragma unroll
            for (int n = 0; n < 2; ++n) {
                ld8(v, Wih0 + (size_t)(rb + n * 16 + col) * II + (w * 32 + kg * 8));
                split8(v, wxh[n], wxl[n]);
                #pragma unroll
                for (int c = 0; c < 4; ++c) {
                    ld8(v, Whh0 + (size_t)(rb + n * 16 + col) * HH + (w * 128 + c * 32 + kg * 8));
                    split8(v, wah[n][c], wal[n][c]);
                }
            }
        } else {
            #pragma unroll
            for (int n = 0; n < 2; ++n)
                #pragma unroll
                for (int c = 0; c < 4; ++c) {
                    ld8(v, Wih1 + (size_t)(rb + n * 16 + col) * HH + (w * 128 + c * 32 + kg * 8));
                    split8(v, wah[n][c], wal[n][c]);
                    ld8(v, Whh1 + (size_t)(rb + n * 16 + col) * HH + (w * 128 + c * 32 + kg * 8));
                    split8(v, wbh[n][c], wbl[n][c]);
                }
        }
    }

    // ---- epilogue role constants ----
    const int ekk = tid >> 4;              // 0..31 (row within WG's chunk)
    const int eb  = tid & 15;              // batch
    const int R   = rb + ekk;
    const float bsum = layer ? (bih1[R] + bhh1[R]) : (bih0[R] + bhh0[R]);
    const int stg_off = (eb + 16 * (ekk >> 3)) * 32 + (ekk & 7) * 2;

    const int tBeg = layer ? 1 : 0;
    const int tEnd = layer ? TT : TT - 1;

    for (int t = tBeg; t <= tEnd; ++t) {
        const char* h1r = h1base + (size_t)(((t - 1) & 3) * 4 + grp) * H1SLOT;
        const char* h2s = h2base + (size_t)((t & 1) * 4 + grp) * H2SLOT; // (t-2)&1 == t&1

        // ---- x prefetch (before poll; input-static) ----
        float xv[8];
        if (layer == 0)
            ld8(xv, x + ((size_t)(b0 + col) * TT + t) * II + (w * 32 + kg * 8));
        asm volatile("" ::: "memory");

        // ---- per-wave fine-grained poll on the 8 chunk footers this wave touches ----
        {
            const int pc = lane & 3;
            bool active = false; unsigned tgt = 0; bool ge = false;
            const char* fp = h1r + 2048;   // placeholder
            if (lane < 4) {                // h1(t-1) chunks: footer == t
                active = (t >= 1); tgt = (unsigned)t; ge = false;
                fp = h1r + (size_t)(w * 4 + pc) * CHK + 2048;
            } else if (lane < 8) {         // h2 chunks
                fp = h2s + (size_t)(w * 4 + pc) * CHK + 2048;
                if (layer == 0) { active = (t >= 4); tgt = (unsigned)(t - 2); ge = true;  }
                else            { active = (t >= 2); tgt = (unsigned)t;       ge = false; }
            }
            if (__any(active ? 1 : 0)) {
                for (;;) {
                    bool ok = true;
                    if (active) {
                        unsigned f = ld_flag(fp);
                        ok = ge ? (f >= tgt) : (f == tgt);
                    }
                    if (__all(ok ? 1 : 0)) break;
                    __builtin_amdgcn_s_sleep(1);
                }
            }
        }
        asm volatile("" ::: "memory");     // pin data loads below the poll

        f32x4 acc0 = {0.f, 0.f, 0.f, 0.f};
        f32x4 acc1 = {0.f, 0.f, 0.f, 0.f};

        if (layer == 0) {
            bf8 xh, xl;
            split8(xv, xh, xl);
            bf8 hh[4], hl[4];
            if (t >= 1) {
                #pragma unroll
                for (int c = 0; c < 4; ++c) {
                    const char* p = h1r + (size_t)(w * 4 + c) * CHK + lane * 32;
                    hh[c] = load_h(p); hl[c] = load_h(p + 16);
                }
            }
            acc0 = MFMA(xh, wxh[0], acc0); acc0 = MFMA(xh, wxl[0], acc0); acc0 = MFMA(xl, wxh[0], acc0);
            acc1 = MFMA(xh, wxh[1], acc1); acc1 = MFMA(xh, wxl[1], acc1); acc1 = MFMA(xl, wxh[1], acc1);
            if (t >= 1) {
                #pragma unroll
                for (int c = 0; c < 4; ++c) {
                    acc0 = MFMA(hh[c], wah[0][c], acc0); acc0 = MFMA(hh[c], wal[0][c], acc0);
                    acc0 = MFMA(hl[c], wah[0][c], acc0);
                    acc1 = MFMA(hh[c], wah[1][c], acc1); acc1 = MFMA(hh[c], wal[1][c], acc1);
                    acc1 = MFMA(hl[c], wah[1][c], acc1);
                }
            }
        } else {
            bf8 hh[4], hl[4], gh[4], gl[4];
            #pragma unroll
            for (int c = 0; c < 4; ++c) {
                const char* p = h1r + (size_t)(w * 4 + c) * CHK + lane * 32;
                hh[c] = load_h(p); hl[c] = load_h(p + 16);
            }
            if (t >= 2) {
                #pragma unroll
                for (int c = 0; c < 4; ++c) {
                    const char* p = h2s + (size_t)(w * 4 + c) * CHK + lane * 32;
                    gh[c] = load_h(p); gl[c] = load_h(p + 16);
                }
            }
            #pragma unroll
            for (int c = 0; c < 4; ++c) {
                acc0 = MFMA(hh[c], wah[0][c], acc0); acc0 = MFMA(hh[c], wal[0][c], acc0);
                acc0 = MFMA(hl[c], wah[0][c], acc0);
                acc1 = MFMA(hh[c], wah[1][c], acc1); acc1 = MFMA(hh[c], wal[1][c], acc1);
                acc1 = MFMA(hl[c], wah[1][c], acc1);
            }
            if (t >= 2) {
                #pragma unroll
                for (int c = 0; c < 4; ++c) {
                    acc0 = MFMA(gh[c], wbh[0][c], acc0); acc0 = MFMA(gh[c], wbl[0][c], acc0);
                    acc0 = MFMA(gl[c], wbh[0][c], acc0);
                    acc1 = MFMA(gh[c], wbh[1][c], acc1); acc1 = MFMA(gh[c], wbl[1][c], acc1);
                    acc1 = MFMA(gl[c], wbh[1][c], acc1);
                }
            }
        }

        // ---- partials to LDS ----
        {
            float* pw = ps + w * 544;
            #pragma unroll
            for (int r = 0; r < 4; ++r) {
                pw[(kg * 4 + r) * 17 + col]       = acc0[r];
                pw[272 + (kg * 4 + r) * 17 + col] = acc1[r];
            }
        }
        __syncthreads();

        // ---- reduce + bias + tanh + hi/lo split -> LDS staging ----
        {
            float s = bsum;
            #pragma unroll
            for (int wv = 0; wv < 8; ++wv)
                s += ps[wv * 544 + (ekk >> 4) * 272 + eb * 17 + (ekk & 15)];
            const float val = tanhf(s);
            const unsigned short hi = f2bf(val);
            const unsigned short lo = f2bf(val - bf2f(hi));
            *(unsigned short*)(staging + stg_off)      = hi;
            *(unsigned short*)(staging + stg_off + 16) = lo;
        }
        __syncthreads();

        // ---- coalesced chunk store (128 x 16B, sc1) + footer publish ----
        char* hw = layer
            ? (h2base + (size_t)(((t - 1) & 1) * 4 + grp) * H2SLOT)
            : (h1base + (size_t)((t & 3) * 4 + grp) * H1SLOT);
        if (tid < 128) {
            const int off = (tid >> 1) * 32 + (tid & 1) * 16;
            const char* src = staging + off;
            store16(hw + (size_t)slot * CHK + off,
                    *(const u64*)src, *(const u64*)(src + 8));
        }
        asm volatile("s_waitcnt vmcnt(0)" ::: "memory");
        __syncthreads();
        if (tid == 0)
            st_flag(hw + (size_t)slot * CHK + 2048, (unsigned)(t + 1));
    }

    // ---- FC gate: all 128 h2 slot-1 chunk footers == TT+1 ----
    if (tid < 128) {
        const char* fp = h2base + (size_t)(4 + (tid >> 5)) * H2SLOT
                       + (size_t)(tid & 31) * CHK + 2048;
        while (ld_flag(fp) != (unsigned)(TT + 1))
            __builtin_amdgcn_s_sleep(2);
    }
    __syncthreads();
    asm volatile("" ::: "memory");

    // ---- FC: block computes out[:, 2*bid .. 2*bid+1] ----
    float* Wlds = shmem + 2304;
    ((float4*)Wlds)[tid] = ((const float4*)(Wfc + (size_t)(2 * bid) * HH))[tid];
    __syncthreads();

    float p0 = 0.f, p1 = 0.f;
    {
        const int gr = lane >> 4, bsub = lane & 15;
        const char* hb = h2base + (size_t)(4 + gr) * H2SLOT;   // slot 1 = (TT-1)&1
        #pragma unroll 4
        for (int k8 = w * 16; k8 < w * 16 + 16; ++k8) {
            const char* p = hb + (size_t)(k8 >> 2) * CHK
                          + (size_t)(bsub + ((k8 & 3) << 4)) * 32;
            bf8 hi = load_h(p), lo = load_h(p + 16);
            const int kb = k8 * 8;
            #pragma unroll
            for (int j = 0; j < 8; ++j) {
                float f = bf2f((unsigned short)hi[j]) + bf2f((unsigned short)lo[j]);
                p0 += f * Wlds[kb + j];
                p1 += f * Wlds[1024 + kb + j];
            }
        }
    }
    __syncthreads();
    shmem[(w * 64 + lane) * 2 + 0] = p0;
    shmem[(w * 64 + lane) * 2 + 1] = p1;
    __syncthreads();
    if (w < 2) {
        float s = bfc[2 * bid + w];
        #pragma unroll
        for (int j = 0; j < 8; ++j) s += shmem[(j * 64 + lane) * 2 + w];
        out[(size_t)lane * OO + 2 * bid + w] = s;
    }
}

extern "C" void kernel_launch(void* const* d_in, const int* in_sizes, int n_in,
                              void* d_out, int out_size, void* d_ws, size_t ws_size,
                              hipStream_t stream) {
    const float* x    = (const float*)d_in[0];
    const float* Wih0 = (const float*)d_in[1];
    const float* Whh0 = (const float*)d_in[2];
    const float* bih0 = (const float*)d_in[3];
    const float* bhh0 = (const float*)d_in[4];
    const float* Wih1 = (const float*)d_in[5];
    const float* Whh1 = (const float*)d_in[6];
    const float* bih1 = (const float*)d_in[7];
    const float* bhh1 = (const float*)d_in[8];
    const float* Wfc  = (const float*)d_in[9];
    const float* bfc  = (const float*)d_in[10];
    float* out = (float*)d_out;
    float* ws  = (float*)d_ws;

    // zero the whole h region (footers included) every call — replay-safe,
    // and the 0xAA poison would spuriously satisfy the >= backpressure check.
    const size_t hbytes = (size_t)16 * H1SLOT + (size_t)8 * H2SLOT;  // 1,622,016 B
    hipMemsetAsync(d_ws, 0, hbytes, stream);

    void* args[] = { (void*)&x,
                     (void*)&Wih0, (void*)&Whh0, (void*)&bih0, (void*)&bhh0,
                     (void*)&Wih1, (void*)&Whh1, (void*)&bih1, (void*)&bhh1,
                     (void*)&Wfc,  (void*)&bfc,  (void*)&out,  (void*)&ws };
    hipLaunchCooperativeKernel((void*)rnn_chunk, dim3(256), dim3(512),
                               args, 0, stream);
}